// Round 14
// baseline (676.875 us; speedup 1.0000x reference)
//
#include <hip/hip_runtime.h>
#include <math.h>

// Problem constants
constexpr int B_ = 4;
constexpr int N_ = 1024;
constexpr int C_ = 384;
constexpr int G_ = 2;
constexpr int K_ = 10;
constexpr int GD_ = 192;   // C_/G_
constexpr int NK_ = N_ * K_;           // 10240
constexpr int M2_ = B_ * G_ * N_ * K_; // 81920
constexpr float SCALE_ = 0.125f;       // 64^-0.5
constexpr float MARGIN_ = 4e-4f;       // 3rd-4th gap flag threshold (~16x comparison err)

// L1 fusion only (L2a/L4 fusions reverted: co-compiled branches share regalloc
// and starve the fatter branch — R12 k_L4 930us, R13 +20us on L2a)
constexpr int L1_PREPM_ = G_ * C_;            // 768 blocks prepM, then prep0
constexpr int L1_GRID_ = L1_PREPM_ + 11;      // 779

// lexicographic (d, idx) compare == lax.top_k(-d) tie-break (lower idx wins)
__device__ __forceinline__ bool lless(double da, int ia, double db, int ib) {
  return (da < db) || (da == db && ia < ib);
}
__device__ __forceinline__ void lmin2(double& rd, int& ri, double ad, int ai,
                                      double bd, int bi) {
  bool t = lless(bd, bi, ad, ai);
  rd = t ? bd : ad; ri = t ? bi : ai;
}
__device__ __forceinline__ void lmax2(double& rd, int& ri, double ad, int ai,
                                      double bd, int bi) {
  bool t = lless(ad, ai, bd, bi);
  rd = t ? bd : ad; ri = t ? bi : ai;
}
// distance-only pair select (fp32 scan: ties handled by MARGIN escalation)
__device__ __forceinline__ void pmin2(float& rd, int& ri, float ad, int ai,
                                      float bd, int bi) {
  bool t = bd < ad;
  rd = t ? bd : ad; ri = t ? bi : ai;
}
__device__ __forceinline__ void pmax2(float& rd, int& ri, float ad, int ai,
                                      float bd, int bi) {
  bool t = ad < bd;
  rd = t ? bd : ad; ri = t ? bi : ai;
}
// fast tanh via hardware exp; |err| ~1e-7 << MARGIN/16 (fix path keeps fp64 tanh)
__device__ __forceinline__ float ftanh(float p) {
  float pc = fminf(fmaxf(p, -15.f), 15.f);
  float e = __expf(2.f * pc);
  return (e - 1.f) * __builtin_amdgcn_rcpf(e + 1.f);
}

// ---------------------------------------------------------------------------
// L1: prepM (+WkT transpose) || prep0 (s64, pos4, cnt=0)
__global__ __launch_bounds__(384) void k_L1(const float* __restrict__ Wvoff,
                                            const float* __restrict__ Wq,
                                            const float* __restrict__ W1,
                                            const float* __restrict__ Wk,
                                            const float* __restrict__ q_pos,
                                            float* __restrict__ M1f,
                                            float* __restrict__ M2f,
                                            float* __restrict__ WkT,
                                            double* __restrict__ s64,
                                            float4* __restrict__ pos4,
                                            int* __restrict__ cnt) {
  if (blockIdx.x < L1_PREPM_) {
    int g = blockIdx.x / C_;
    int k = blockIdx.x % C_;
    int c = threadIdx.x;
    if (g == 0) WkT[c * C_ + k] = Wk[k * C_ + c];
    const float* wv = Wvoff + k * C_ + g * GD_;
    const float* wq = Wq + k * C_ + g * GD_;
    double a1 = 0.0, a2 = 0.0;
    for (int d = 0; d < GD_; d++) {
      a1 += (double)wv[d] * (double)W1[d * C_ + c];
      a2 += (double)wq[d] * (double)W1[(GD_ + d) * C_ + c];
    }
    M1f[(g * C_ + k) * C_ + c] = (float)a1;
    M2f[(g * C_ + k) * C_ + c] = (float)a2;
  } else {
    int i = (blockIdx.x - L1_PREPM_) * 384 + threadIdx.x;
    if (i == 0) cnt[0] = 0;
    if (i >= B_ * N_) return;
    float x = q_pos[3 * i], y = q_pos[3 * i + 1], z = q_pos[3 * i + 2];
    double v = (double)x * x + (double)y * y + (double)z * z;
    s64[i] = v;
    pos4[i] = make_float4(x, y, z, (float)v);
  }
}

// ---------------------------------------------------------------------------
// KNN-10, wave-parallel fp64, standalone (256 thr / 4 waves)
__global__ __launch_bounds__(256) void k_knn10_w(const float* __restrict__ q_pos,
                                                 const double* __restrict__ s,
                                                 int* __restrict__ idx10) {
  int wid = (blockIdx.x * blockDim.x + threadIdx.x) >> 6;
  int lane = threadIdx.x & 63;
  if (wid >= B_ * N_) return;
  int b = wid / N_;
  double px = q_pos[3 * wid], py = q_pos[3 * wid + 1], pz = q_pos[3 * wid + 2];
  double sm = s[wid];
  const float* bp = q_pos + b * N_ * 3;
  const double* bs = s + b * N_;
  double d[K_]; int ix[K_];
  #pragma unroll
  for (int j = 0; j < K_; j++) { d[j] = INFINITY; ix[j] = 0x7fffffff; }
  for (int n0 = 0; n0 < N_; n0 += 64) {
    int n = n0 + lane;
    double dot = px * (double)bp[3 * n] + py * (double)bp[3 * n + 1] +
                 pz * (double)bp[3 * n + 2];
    double v = (sm - 2.0 * dot) + bs[n];
    bool c[K_];
    #pragma unroll
    for (int j = 0; j < K_; j++) c[j] = lless(v, n, d[j], ix[j]);
    #pragma unroll
    for (int j = K_ - 1; j >= 1; j--) {
      d[j]  = c[j] ? (c[j - 1] ? d[j - 1] : v) : d[j];
      ix[j] = c[j] ? (c[j - 1] ? ix[j - 1] : n) : ix[j];
    }
    d[0]  = c[0] ? v : d[0];
    ix[0] = c[0] ? n : ix[0];
  }
  #pragma unroll
  for (int off = 1; off < 64; off <<= 1) {
    double bd[K_]; int bi[K_];
    #pragma unroll
    for (int j = 0; j < K_; j++) {
      bd[j] = __shfl_xor(d[j], off);
      bi[j] = __shfl_xor(ix[j], off);
    }
    double md[K_]; int mi[K_];
    #pragma unroll
    for (int r = 0; r < K_; r++) {
      double m; int mj;
      lmin2(m, mj, d[r], ix[r], bd[r], bi[r]);
      #pragma unroll
      for (int j = 1; j <= r; j++) {
        double t; int ti;
        lmax2(t, ti, d[j - 1], ix[j - 1], bd[r - j], bi[r - j]);
        lmin2(m, mj, m, mj, t, ti);
      }
      md[r] = m; mi[r] = mj;
    }
    #pragma unroll
    for (int j = 0; j < K_; j++) { d[j] = md[j]; ix[j] = mi[j]; }
  }
  if (lane == 0) {
    #pragma unroll
    for (int j = 0; j < K_; j++) idx10[wid * K_ + j] = ix[j];
  }
}

// ---------------------------------------------------------------------------
// fp32 GEMM, scalar-A: out[M x 384] = A @ W (standalone, TM=8)
__global__ __launch_bounds__(384) void k_gemmSA(const float* __restrict__ A,
                                                const float* __restrict__ W,
                                                float* __restrict__ out) {
  int c = threadIdx.x;
  int r0 = blockIdx.x * 8;
  float acc[8];
  #pragma unroll
  for (int r = 0; r < 8; r++) acc[r] = 0.f;
  #pragma unroll 4
  for (int j = 0; j < C_; j++) {
    float w = W[j * C_ + c];
    #pragma unroll
    for (int r = 0; r < 8; r++) acc[r] = fmaf(A[(r0 + r) * C_ + j], w, acc[r]);
  }
  #pragma unroll
  for (int r = 0; r < 8; r++) out[(r0 + r) * C_ + c] = acc[r];
}

// ---------------------------------------------------------------------------
// Y32: TM=16 (halves per-block M streaming: 2.4 GB -> 1.2 GB L2 traffic)
__global__ __launch_bounds__(384) void k_Y32(const float* __restrict__ q,
                                             const float* __restrict__ M1f,
                                             const float* __restrict__ M2f,
                                             float* __restrict__ Y1f,
                                             float* __restrict__ Y2f) {
  constexpr int TM = 16;
  int c = threadIdx.x;
  int g = blockIdx.y;
  int r0 = blockIdx.x * TM;
  float a1[TM], a2[TM];
  #pragma unroll
  for (int r = 0; r < TM; r++) { a1[r] = 0.f; a2[r] = 0.f; }
  const float* m1 = M1f + (size_t)(g * C_) * C_ + c;
  const float* m2 = M2f + (size_t)(g * C_) * C_ + c;
  for (int k = 0; k < C_; k++) {
    float v1 = m1[(size_t)k * C_];
    float v2 = m2[(size_t)k * C_];
    #pragma unroll
    for (int r = 0; r < TM; r++) {
      float av = q[(r0 + r) * C_ + k];
      a1[r] = fmaf(av, v1, a1[r]);
      a2[r] = fmaf(av, v2, a2[r]);
    }
  }
  #pragma unroll
  for (int r = 0; r < TM; r++) {
    Y1f[((size_t)(r0 + r) * G_ + g) * C_ + c] = a1[r];
    Y2f[((size_t)(r0 + r) * G_ + g) * C_ + c] = a2[r];
  }
}

// ---------------------------------------------------------------------------
// FUSED fp32 MLP + top-3+r4 scan. 256 thr / 4 waves (81% occupancy config).
__global__ __launch_bounds__(256) void k_mlptop4(const float* __restrict__ Y1f,
                                                 const float* __restrict__ Y2f,
                                                 const int* __restrict__ idx10,
                                                 const float* __restrict__ q_pos,
                                                 const float* __restrict__ b1,
                                                 const float* __restrict__ ln_g,
                                                 const float* __restrict__ ln_b,
                                                 const float* __restrict__ W2,
                                                 const float4* __restrict__ pos4,
                                                 const float* __restrict__ q,
                                                 float* __restrict__ interp,
                                                 int* __restrict__ flags,
                                                 int* __restrict__ cnt) {
  int w_ = threadIdx.x >> 6, l = threadIdx.x & 63;
  int row = blockIdx.x * 4 + w_;
  int k = row % K_; int t = row / K_;
  int n = t % N_; t /= N_;
  int g = t % G_; int b = t / G_;
  int j = idx10[(b * N_ + n) * K_ + k];
  const float* y1 = Y1f + ((size_t)(b * N_ + j) * G_ + g) * C_;
  const float* y2 = Y2f + ((size_t)(b * N_ + n) * G_ + g) * C_;
  float x[6];
  #pragma unroll
  for (int jj = 0; jj < 6; jj++) {
    int col = l + 64 * jj;
    x[jj] = y1[col] + y2[col] + b1[col];
  }
  float sum = ((((x[0] + x[1]) + x[2]) + x[3]) + x[4]) + x[5];
  #pragma unroll
  for (int off = 1; off < 64; off <<= 1) sum += __shfl_xor(sum, off);
  float mu = sum * (1.0f / 384.0f);
  float sq = 0.f;
  #pragma unroll
  for (int jj = 0; jj < 6; jj++) { float dd = x[jj] - mu; sq = fmaf(dd, dd, sq); }
  #pragma unroll
  for (int off = 1; off < 64; off <<= 1) sq += __shfl_xor(sq, off);
  float var = sq * (1.0f / 384.0f);
  float rstd = 1.0f / sqrtf(var + 1e-5f);
  float ge[6];
  #pragma unroll
  for (int jj = 0; jj < 6; jj++) {
    int col = l + 64 * jj;
    float nv = (x[jj] - mu) * rstd * ln_g[col] + ln_b[col];
    ge[jj] = 0.5f * nv * (1.0f + erff(nv * 0.70710678118654752f));
  }
  float o3[3];
  #pragma unroll
  for (int o = 0; o < 3; o++) {
    float p = 0.f;
    #pragma unroll
    for (int jj = 0; jj < 6; jj++) {
      int col = l + 64 * jj;
      p = fmaf(ge[jj], W2[col * 3 + o], p);
    }
    #pragma unroll
    for (int off = 1; off < 64; off <<= 1) p += __shfl_xor(p, off);
    o3[o] = ftanh(p);
  }
  int gi = b * N_ + j;
  float px = q_pos[gi * 3 + 0] + o3[0];
  float py = q_pos[gi * 3 + 1] + o3[1];
  float pz = q_pos[gi * 3 + 2] + o3[2];
  float sp = fmaf(px, px, fmaf(py, py, pz * pz));
  float nx = -2.0f * px, ny = -2.0f * py, nz = -2.0f * pz;
  const float4* p4 = pos4 + b * N_;
  float d0 = INFINITY, d1 = INFINITY, d2 = INFINITY, r4 = INFINITY;
  int i0 = 0x7fffffff, i1 = 0x7fffffff, i2 = 0x7fffffff;
  for (int n0 = 0; n0 < N_; n0 += 64) {
    int nn = n0 + l;
    float4 pv = p4[nn];
    float v = fmaf(nx, pv.x, fmaf(ny, pv.y, fmaf(nz, pv.z, sp + pv.w)));
    bool c0 = v < d0, c1 = v < d1, c2 = v < d2;
    float disp = c2 ? d2 : v;
    r4 = fminf(r4, disp);
    d2 = c2 ? (c1 ? d1 : v) : d2;
    i2 = c2 ? (c1 ? i1 : nn) : i2;
    d1 = c1 ? (c0 ? d0 : v) : d1;
    i1 = c1 ? (c0 ? i0 : nn) : i1;
    d0 = c0 ? v : d0;
    i0 = c0 ? nn : i0;
  }
  #pragma unroll
  for (int off = 1; off < 64; off <<= 1) {
    float e0 = __shfl_xor(d0, off), e1 = __shfl_xor(d1, off), e2 = __shfl_xor(d2, off);
    float er = __shfl_xor(r4, off);
    int j0 = __shfl_xor(i0, off), j1 = __shfl_xor(i1, off), j2 = __shfl_xor(i2, off);
    float va = fmaxf(d0, e2), vb = fmaxf(d1, e1), vc = fmaxf(d2, e0);
    float r4n = fminf(fminf(r4, er), fminf(fminf(va, vb), vc));
    float m0d, t1d, u1d, m1d, t2a, t2b, u2d, w2d, m2d;
    int m0i, t1i, u1i, m1i, t2ai, t2bi, u2i, w2i, m2i;
    pmin2(m0d, m0i, d0, i0, e0, j0);
    pmax2(t1d, t1i, d0, i0, e0, j0);
    pmin2(u1d, u1i, d1, i1, e1, j1);
    pmin2(m1d, m1i, u1d, u1i, t1d, t1i);
    pmax2(t2a, t2ai, d1, i1, e0, j0);
    pmax2(t2b, t2bi, d0, i0, e1, j1);
    pmin2(u2d, u2i, d2, i2, e2, j2);
    pmin2(w2d, w2i, t2a, t2ai, t2b, t2bi);
    pmin2(m2d, m2i, u2d, u2i, w2d, w2i);
    d0 = m0d; i0 = m0i; d1 = m1d; i1 = m1i; d2 = m2d; i2 = m2i; r4 = r4n;
  }
  if (r4 - d2 < MARGIN_) {
    if (l == 0) {
      int pos = atomicAdd(cnt, 1);
      flags[pos] = row;
    }
    return;
  }
  float r0 = 1.0f / (d0 + 1e-8f);
  float r1 = 1.0f / (d1 + 1e-8f);
  float r2 = 1.0f / (d2 + 1e-8f);
  float rs = (r0 + r1) + r2;
  float w0 = r0 / rs, w1 = r1 / rs, w2 = r2 / rs;
  const float* qb = q + (size_t)b * N_ * C_ + g * GD_;
  const float* p0 = qb + (size_t)i0 * C_;
  const float* p1 = qb + (size_t)i1 * C_;
  const float* p2 = qb + (size_t)i2 * C_;
  float* op = interp + (((size_t)(b * N_ + n) * K_ + k) * C_) + g * GD_;
  #pragma unroll
  for (int cc0 = 0; cc0 < GD_; cc0 += 64) {
    int cc = cc0 + l;
    op[cc] = (w0 * p0[cc] + w1 * p1[cc]) + w2 * p2[cc];
  }
}

// ---------------------------------------------------------------------------
// Standalone fp64 fix (v-route), 256 thr, full VGPR budget
__global__ __launch_bounds__(256) void k_fix(const int* __restrict__ cnt,
                                             const int* __restrict__ flags,
                                             const float* __restrict__ q,
                                             const float* __restrict__ Wvoff,
                                             const float* __restrict__ Wq,
                                             const float* __restrict__ W1,
                                             const int* __restrict__ idx10,
                                             const float* __restrict__ q_pos,
                                             const double* __restrict__ s64,
                                             const float* __restrict__ b1,
                                             const float* __restrict__ ln_g,
                                             const float* __restrict__ ln_b,
                                             const float* __restrict__ W2,
                                             float* __restrict__ interp) {
  __shared__ double vbuf[4][2][GD_];   // 12.3 KB, per-wave scratch
  int w_ = threadIdx.x >> 6;
  int gwid = blockIdx.x * 4 + w_;
  int lane = threadIdx.x & 63;
  int nwaves = gridDim.x * 4;
  int total = cnt[0];
  for (int i = gwid; i < total; i += nwaves) {
    int wid = __builtin_amdgcn_readfirstlane(flags[i]);
    int m = wid % NK_; int t = wid / NK_;
    int g = t % G_; int b = t / G_;
    int n_ = m / K_, k_ = m % K_;
    int j = __builtin_amdgcn_readfirstlane(idx10[(b * N_ + n_) * K_ + k_]);
    const float* qj = q + (size_t)(b * N_ + j) * C_;   // wave-uniform
    const float* qn = q + (size_t)(b * N_ + n_) * C_;
    const float* wvo = Wvoff + g * GD_;
    const float* wqg = Wq + g * GD_;
    double a0 = 0.0, a1 = 0.0, a2 = 0.0, b0 = 0.0, b1a = 0.0, b2 = 0.0;
    for (int tt = 0; tt < C_; tt++) {
      double qjt = (double)qj[tt];
      double qnt = (double)qn[tt];
      const float* r1 = wvo + (size_t)tt * C_;
      const float* r2 = wqg + (size_t)tt * C_;
      a0 += qjt * (double)r1[lane];
      a1 += qjt * (double)r1[lane + 64];
      a2 += qjt * (double)r1[lane + 128];
      b0 += qnt * (double)r2[lane];
      b1a += qnt * (double)r2[lane + 64];
      b2 += qnt * (double)r2[lane + 128];
    }
    vbuf[w_][0][lane] = a0; vbuf[w_][0][lane + 64] = a1; vbuf[w_][0][lane + 128] = a2;
    vbuf[w_][1][lane] = b0; vbuf[w_][1][lane + 64] = b1a; vbuf[w_][1][lane + 128] = b2;
    double x[6];
    #pragma unroll
    for (int jj = 0; jj < 6; jj++) x[jj] = 0.0;
    for (int d = 0; d < GD_; d++) {
      double v1d = vbuf[w_][0][d];
      double v2d = vbuf[w_][1][d];
      const float* w1t = W1 + (size_t)d * C_;
      const float* w1b = W1 + (size_t)(GD_ + d) * C_;
      #pragma unroll
      for (int jj = 0; jj < 6; jj++) {
        int col = lane + 64 * jj;
        x[jj] += v1d * (double)w1t[col] + v2d * (double)w1b[col];
      }
    }
    #pragma unroll
    for (int jj = 0; jj < 6; jj++) x[jj] += (double)b1[lane + 64 * jj];
    double sum = ((((x[0] + x[1]) + x[2]) + x[3]) + x[4]) + x[5];
    #pragma unroll
    for (int off = 1; off < 64; off <<= 1) sum += __shfl_xor(sum, off);
    double mu = sum / 384.0;
    double sq = 0.0;
    #pragma unroll
    for (int jj = 0; jj < 6; jj++) { double dd = x[jj] - mu; sq += dd * dd; }
    #pragma unroll
    for (int off = 1; off < 64; off <<= 1) sq += __shfl_xor(sq, off);
    double var = sq / 384.0;
    double rstd = 1.0 / sqrt(var + 1e-5);
    double ge[6];
    #pragma unroll
    for (int jj = 0; jj < 6; jj++) {
      int col = lane + 64 * jj;
      double nv = (x[jj] - mu) * rstd * (double)ln_g[col] + (double)ln_b[col];
      ge[jj] = 0.5 * nv * (1.0 + erf(nv * 0.70710678118654752440));
    }
    double o3[3];
    #pragma unroll
    for (int o = 0; o < 3; o++) {
      double p = 0.0;
      #pragma unroll
      for (int jj = 0; jj < 6; jj++) {
        int col = lane + 64 * jj;
        p += ge[jj] * (double)W2[col * 3 + o];
      }
      #pragma unroll
      for (int off = 1; off < 64; off <<= 1) p += __shfl_xor(p, off);
      o3[o] = tanh(p);
    }
    int gi = b * N_ + j;
    double px = (double)q_pos[gi * 3 + 0] + o3[0];
    double py = (double)q_pos[gi * 3 + 1] + o3[1];
    double pz = (double)q_pos[gi * 3 + 2] + o3[2];
    double sp = px * px + py * py + pz * pz;
    const float* bp = q_pos + b * N_ * 3;
    const double* bs = s64 + b * N_;
    double d0 = INFINITY, d1 = INFINITY, d2 = INFINITY;
    int i0 = 0x7fffffff, i1 = 0x7fffffff, i2 = 0x7fffffff;
    for (int n = lane; n < N_; n += 64) {
      double dot = px * (double)bp[3 * n] + py * (double)bp[3 * n + 1] +
                   pz * (double)bp[3 * n + 2];
      double dd = (sp - 2.0 * dot) + bs[n];
      bool c0 = lless(dd, n, d0, i0);
      bool c1 = lless(dd, n, d1, i1);
      bool c2 = lless(dd, n, d2, i2);
      double nd2 = c2 ? (c1 ? d1 : dd) : d2; int ni2 = c2 ? (c1 ? i1 : n) : i2;
      double nd1 = c1 ? (c0 ? d0 : dd) : d1; int ni1 = c1 ? (c0 ? i0 : n) : i1;
      double nd0 = c0 ? dd : d0;             int ni0 = c0 ? n : i0;
      d0 = nd0; d1 = nd1; d2 = nd2; i0 = ni0; i1 = ni1; i2 = ni2;
    }
    #pragma unroll
    for (int off = 1; off < 64; off <<= 1) {
      double e0 = __shfl_xor(d0, off), e1 = __shfl_xor(d1, off), e2 = __shfl_xor(d2, off);
      int j0 = __shfl_xor(i0, off), j1 = __shfl_xor(i1, off), j2 = __shfl_xor(i2, off);
      double mnd, mxd, p1d, q1d, q2d, q3d, q4d, t1d, t2d;
      int mni, mxi, p1i, q1i, q2i, q3i, q4i, t1i, t2i;
      lmin2(mnd, mni, d0, i0, e0, j0);
      lmax2(mxd, mxi, d0, i0, e0, j0);
      lmin2(p1d, p1i, d1, i1, e1, j1);
      lmin2(t1d, t1i, p1d, p1i, mxd, mxi);
      lmax2(q1d, q1i, d1, i1, e0, j0);
      lmax2(q2d, q2i, d0, i0, e1, j1);
      lmin2(q3d, q3i, q1d, q1i, q2d, q2i);
      lmin2(q4d, q4i, d2, i2, e2, j2);
      lmin2(t2d, t2i, q3d, q3i, q4d, q4i);
      d0 = mnd; i0 = mni; d1 = t1d; i1 = t1i; d2 = t2d; i2 = t2i;
    }
    double r0 = 1.0 / (d0 + 1e-8);
    double r1 = 1.0 / (d1 + 1e-8);
    double r2 = 1.0 / (d2 + 1e-8);
    double rs = (r0 + r1) + r2;
    float w0 = (float)(r0 / rs), w1 = (float)(r1 / rs), w2 = (float)(r2 / rs);
    const float* qb = q + (size_t)b * N_ * C_ + g * GD_;
    const float* p0 = qb + (size_t)i0 * C_;
    const float* p1 = qb + (size_t)i1 * C_;
    const float* p2 = qb + (size_t)i2 * C_;
    float* op = interp + (((size_t)(b * N_ + n_) * K_ + k_) * C_) + g * GD_;
    #pragma unroll
    for (int cc0 = 0; cc0 < GD_; cc0 += 64) {
      int cc = cc0 + lane;
      op[cc] = (w0 * p0[cc] + w1 * p1[cc]) + w2 * p2[cc];
    }
  }
}

// ---------------------------------------------------------------------------
// Standalone k_U: U[bn][h][c] = sum_d qp[bn, h*64+d] * Wk[c, h*64+d]
__global__ __launch_bounds__(384) void k_U(const float* __restrict__ qp,
                                           const float* __restrict__ WkT,
                                           float* __restrict__ U) {
  int c = threadIdx.x;
  int r0 = blockIdx.x * 8;
  for (int h = 0; h < 6; h++) {
    float acc[8];
    #pragma unroll
    for (int r = 0; r < 8; r++) acc[r] = 0.f;
    #pragma unroll 4
    for (int dd = 0; dd < 64; dd++) {
      float w = WkT[(h * 64 + dd) * C_ + c];
      #pragma unroll
      for (int r = 0; r < 8; r++)
        acc[r] = fmaf(qp[(r0 + r) * C_ + h * 64 + dd], w, acc[r]);
    }
    #pragma unroll
    for (int r = 0; r < 8; r++) U[((size_t)(r0 + r) * 6 + h) * C_ + c] = acc[r];
  }
}

// ---------------------------------------------------------------------------
// attention per bn (ONE wave, 6 heads serial; interp row cached in VGPRs)
__global__ __launch_bounds__(384) void k_attn2(const float* __restrict__ interp,
                                               float* __restrict__ Umix) {
  int bn = blockIdx.x * 6 + (threadIdx.x >> 6);
  int lane = threadIdx.x & 63;
  if (bn >= B_ * N_) return;
  float ipv[K_][6];
  const float* ip0 = interp + (size_t)bn * K_ * C_;
  #pragma unroll
  for (int k = 0; k < K_; k++) {
    #pragma unroll
    for (int j = 0; j < 6; j++) ipv[k][j] = ip0[k * C_ + lane + 64 * j];
  }
  float* ubase = Umix + (size_t)bn * 6 * C_;
  for (int h = 0; h < 6; h++) {
    float u[6];
    #pragma unroll
    for (int j = 0; j < 6; j++) u[j] = ubase[h * C_ + lane + 64 * j];
    float logit[K_];
    #pragma unroll
    for (int k = 0; k < K_; k++) {
      float p = 0.f;
      #pragma unroll
      for (int j = 0; j < 6; j++) p = fmaf(ipv[k][j], u[j], p);
      #pragma unroll
      for (int off = 1; off < 64; off <<= 1) p += __shfl_xor(p, off);
      logit[k] = p * SCALE_;
    }
    float mx = logit[0];
    #pragma unroll
    for (int k = 1; k < K_; k++) mx = fmaxf(mx, logit[k]);
    float e[K_], se = 0.f;
    #pragma unroll
    for (int k = 0; k < K_; k++) { e[k] = __expf(logit[k] - mx); se += e[k]; }
    float inv = 1.0f / se;
    #pragma unroll
    for (int k = 0; k < K_; k++) e[k] *= inv;
    #pragma unroll
    for (int j = 0; j < 6; j++) {
      float mv = 0.f;
      #pragma unroll
      for (int k = 0; k < K_; k++) mv = fmaf(e[k], ipv[k][j], mv);
      ubase[h * C_ + lane + 64 * j] = mv;
    }
  }
}

// ---------------------------------------------------------------------------
// outproj: attn_out = mix @ Wv (per-head) -> LDS -> out = attn_out @ Wproj + b
__global__ __launch_bounds__(384) void k_outproj(const float* __restrict__ mix,
                                                 const float* __restrict__ Wv,
                                                 const float* __restrict__ Wproj,
                                                 const float* __restrict__ bproj,
                                                 float* __restrict__ out) {
  __shared__ float ao[8][C_];
  int c = threadIdx.x;
  int h = __builtin_amdgcn_readfirstlane(threadIdx.x) >> 6;  // wave-uniform
  int r0 = blockIdx.x * 8;
  float acc[8];
  #pragma unroll
  for (int r = 0; r < 8; r++) acc[r] = 0.f;
  #pragma unroll 4
  for (int ci = 0; ci < C_; ci++) {
    float w = Wv[ci * C_ + c];
    #pragma unroll
    for (int r = 0; r < 8; r++)
      acc[r] = fmaf(mix[((size_t)(r0 + r) * 6 + h) * C_ + ci], w, acc[r]);
  }
  #pragma unroll
  for (int r = 0; r < 8; r++) ao[r][c] = acc[r];
  __syncthreads();
  float a2[8];
  #pragma unroll
  for (int r = 0; r < 8; r++) a2[r] = 0.f;
  #pragma unroll 4
  for (int ci = 0; ci < C_; ci++) {
    float w = Wproj[ci * C_ + c];
    #pragma unroll
    for (int r = 0; r < 8; r++) a2[r] = fmaf(ao[r][ci], w, a2[r]);
  }
  float bv = bproj[c];
  #pragma unroll
  for (int r = 0; r < 8; r++) out[(size_t)(r0 + r) * C_ + c] = a2[r] + bv;
}

// ---------------------------------------------------------------------------
extern "C" void kernel_launch(void* const* d_in, const int* in_sizes, int n_in,
                              void* d_out, int out_size, void* d_ws, size_t ws_size,
                              hipStream_t stream) {
  const float* q     = (const float*)d_in[0];
  const float* q_pos = (const float*)d_in[1];
  const float* Wq    = (const float*)d_in[2];
  const float* Wk    = (const float*)d_in[3];
  const float* Wv    = (const float*)d_in[4];
  const float* Wvoff = (const float*)d_in[5];
  const float* W1    = (const float*)d_in[6];
  const float* b1    = (const float*)d_in[7];
  const float* ln_g  = (const float*)d_in[8];
  const float* ln_b  = (const float*)d_in[9];
  const float* W2    = (const float*)d_in[10];
  const float* Wproj = (const float*)d_in[11];
  const float* bproj = (const float*)d_in[12];
  float* out = (float*)d_out;

  char* ws = (char*)d_ws;
  // U0 (38 MB): Y1f/Y2f/M1f/M2f during prep+scan; reused as Umix from k_U on.
  char* U0 = ws; ws += 38 * 1024 * 1024;
  float*  Y1f    = (float*)(U0);                         // 12.58 MB
  float*  Y2f    = (float*)(U0 + 12582912);              // 12.58 MB
  float*  M1f    = (float*)(U0 + 25165824);              // 1.18 MB
  float*  M2f    = (float*)(U0 + 26345472);              // 1.18 MB
  float*  Umix   = (float*)U0;                           // 37.75 MB (from k_U)
  // Persistent (outside U0; live across the U0 reuse boundary)
  double* s64    = (double*)ws; ws += (size_t)B_ * N_ * 8;              // 32 KB
  float*  qp32   = (float*)ws;  ws += (size_t)B_ * N_ * C_ * 4;         // 6.29 MB
  float*  interp = (float*)ws;  ws += (size_t)B_ * N_ * K_ * C_ * 4;    // 62.9 MB
  float*  WkT    = (float*)ws;  ws += (size_t)C_ * C_ * 4;              // 0.59 MB
  int*    idx10  = (int*)ws;    ws += (size_t)B_ * N_ * K_ * 4;         // 160 KB
  int*    flags  = (int*)ws;    ws += (size_t)M2_ * 4;                  // 320 KB
  float4* pos4   = (float4*)ws; ws += (size_t)B_ * N_ * 16;             // 64 KB
  int*    cnt    = (int*)ws;    ws += 256;                              // 4 B

  k_L1<<<L1_GRID_, 384, 0, stream>>>(Wvoff, Wq, W1, Wk, q_pos, M1f, M2f, WkT,
                                     s64, pos4, cnt);
  k_knn10_w<<<B_ * N_ / 4, 256, 0, stream>>>(q_pos, s64, idx10);
  k_gemmSA<<<B_ * N_ / 8, 384, 0, stream>>>(q, Wq, qp32);
  k_Y32<<<dim3(B_ * N_ / 16, G_), 384, 0, stream>>>(q, M1f, M2f, Y1f, Y2f);
  k_mlptop4<<<M2_ / 4, 256, 0, stream>>>(Y1f, Y2f, idx10, q_pos, b1, ln_g, ln_b,
                                         W2, pos4, q, interp, flags, cnt);
  k_fix<<<512, 256, 0, stream>>>(cnt, flags, q, Wvoff, Wq, W1, idx10, q_pos, s64,
                                 b1, ln_g, ln_b, W2, interp);
  k_U<<<B_ * N_ / 8, 384, 0, stream>>>(qp32, WkT, Umix);
  k_attn2<<<(B_ * N_ + 5) / 6, 384, 0, stream>>>(interp, Umix);
  k_outproj<<<B_ * N_ / 8, 384, 0, stream>>>(Umix, Wv, Wproj, bproj, out);
}

// Round 16
// 610.140 us; speedup vs baseline: 1.1094x; 1.1094x over previous
//
#include <hip/hip_runtime.h>
#include <math.h>

// Problem constants
constexpr int B_ = 4;
constexpr int N_ = 1024;
constexpr int C_ = 384;
constexpr int G_ = 2;
constexpr int K_ = 10;
constexpr int GD_ = 192;   // C_/G_
constexpr int NK_ = N_ * K_;           // 10240
constexpr int M2_ = B_ * G_ * N_ * K_; // 81920
constexpr float SCALE_ = 0.125f;       // 64^-0.5
constexpr float MARGIN_ = 4e-4f;       // 3rd-4th gap flag threshold (~16x comparison err)

// L1 fusion only (L2a/L4 fusions reverted: co-compiled branches share regalloc
// and starve the fatter branch — R12 k_L4 930us). Y32+qpGEMM fusion is safe:
// both branches are fp32 scalar-A GEMMs with ~equal register pressure.
constexpr int L1_PREPM_ = G_ * C_;            // 768 blocks prepM, then prep0
constexpr int L1_GRID_ = L1_PREPM_ + 11;      // 779

// lexicographic (d, idx) compare == lax.top_k(-d) tie-break (lower idx wins)
__device__ __forceinline__ bool lless(double da, int ia, double db, int ib) {
  return (da < db) || (da == db && ia < ib);
}
__device__ __forceinline__ void lmin2(double& rd, int& ri, double ad, int ai,
                                      double bd, int bi) {
  bool t = lless(bd, bi, ad, ai);
  rd = t ? bd : ad; ri = t ? bi : ai;
}
__device__ __forceinline__ void lmax2(double& rd, int& ri, double ad, int ai,
                                      double bd, int bi) {
  bool t = lless(ad, ai, bd, bi);
  rd = t ? bd : ad; ri = t ? bi : ai;
}
// distance-only pair select (fp32 scan: ties handled by MARGIN escalation)
__device__ __forceinline__ void pmin2(float& rd, int& ri, float ad, int ai,
                                      float bd, int bi) {
  bool t = bd < ad;
  rd = t ? bd : ad; ri = t ? bi : ai;
}
__device__ __forceinline__ void pmax2(float& rd, int& ri, float ad, int ai,
                                      float bd, int bi) {
  bool t = ad < bd;
  rd = t ? bd : ad; ri = t ? bi : ai;
}
// fast tanh via hardware exp; |err| ~1e-7 << MARGIN/16 (fix path keeps fp64 tanh)
__device__ __forceinline__ float ftanh(float p) {
  float pc = fminf(fmaxf(p, -15.f), 15.f);
  float e = __expf(2.f * pc);
  return (e - 1.f) * __builtin_amdgcn_rcpf(e + 1.f);
}

// ---------------------------------------------------------------------------
// L1: prepM (+WkT transpose) || prep0 (s64, pos4, cnt=0)
__global__ __launch_bounds__(384) void k_L1(const float* __restrict__ Wvoff,
                                            const float* __restrict__ Wq,
                                            const float* __restrict__ W1,
                                            const float* __restrict__ Wk,
                                            const float* __restrict__ q_pos,
                                            float* __restrict__ M1f,
                                            float* __restrict__ M2f,
                                            float* __restrict__ WkT,
                                            double* __restrict__ s64,
                                            float4* __restrict__ pos4,
                                            int* __restrict__ cnt) {
  if (blockIdx.x < L1_PREPM_) {
    int g = blockIdx.x / C_;
    int k = blockIdx.x % C_;
    int c = threadIdx.x;
    if (g == 0) WkT[c * C_ + k] = Wk[k * C_ + c];
    const float* wv = Wvoff + k * C_ + g * GD_;
    const float* wq = Wq + k * C_ + g * GD_;
    double a1 = 0.0, a2 = 0.0;
    for (int d = 0; d < GD_; d++) {
      a1 += (double)wv[d] * (double)W1[d * C_ + c];
      a2 += (double)wq[d] * (double)W1[(GD_ + d) * C_ + c];
    }
    M1f[(g * C_ + k) * C_ + c] = (float)a1;
    M2f[(g * C_ + k) * C_ + c] = (float)a2;
  } else {
    int i = (blockIdx.x - L1_PREPM_) * 384 + threadIdx.x;
    if (i == 0) cnt[0] = 0;
    if (i >= B_ * N_) return;
    float x = q_pos[3 * i], y = q_pos[3 * i + 1], z = q_pos[3 * i + 2];
    double v = (double)x * x + (double)y * y + (double)z * z;
    s64[i] = v;
    pos4[i] = make_float4(x, y, z, (float)v);
  }
}

// ---------------------------------------------------------------------------
// KNN-10, wave-parallel fp64, standalone (256 thr / 4 waves)
__global__ __launch_bounds__(256) void k_knn10_w(const float* __restrict__ q_pos,
                                                 const double* __restrict__ s,
                                                 int* __restrict__ idx10) {
  int wid = (blockIdx.x * blockDim.x + threadIdx.x) >> 6;
  int lane = threadIdx.x & 63;
  if (wid >= B_ * N_) return;
  int b = wid / N_;
  double px = q_pos[3 * wid], py = q_pos[3 * wid + 1], pz = q_pos[3 * wid + 2];
  double sm = s[wid];
  const float* bp = q_pos + b * N_ * 3;
  const double* bs = s + b * N_;
  double d[K_]; int ix[K_];
  #pragma unroll
  for (int j = 0; j < K_; j++) { d[j] = INFINITY; ix[j] = 0x7fffffff; }
  for (int n0 = 0; n0 < N_; n0 += 64) {
    int n = n0 + lane;
    double dot = px * (double)bp[3 * n] + py * (double)bp[3 * n + 1] +
                 pz * (double)bp[3 * n + 2];
    double v = (sm - 2.0 * dot) + bs[n];
    bool c[K_];
    #pragma unroll
    for (int j = 0; j < K_; j++) c[j] = lless(v, n, d[j], ix[j]);
    #pragma unroll
    for (int j = K_ - 1; j >= 1; j--) {
      d[j]  = c[j] ? (c[j - 1] ? d[j - 1] : v) : d[j];
      ix[j] = c[j] ? (c[j - 1] ? ix[j - 1] : n) : ix[j];
    }
    d[0]  = c[0] ? v : d[0];
    ix[0] = c[0] ? n : ix[0];
  }
  #pragma unroll
  for (int off = 1; off < 64; off <<= 1) {
    double bd[K_]; int bi[K_];
    #pragma unroll
    for (int j = 0; j < K_; j++) {
      bd[j] = __shfl_xor(d[j], off);
      bi[j] = __shfl_xor(ix[j], off);
    }
    double md[K_]; int mi[K_];
    #pragma unroll
    for (int r = 0; r < K_; r++) {
      double m; int mj;
      lmin2(m, mj, d[r], ix[r], bd[r], bi[r]);
      #pragma unroll
      for (int j = 1; j <= r; j++) {
        double t; int ti;
        lmax2(t, ti, d[j - 1], ix[j - 1], bd[r - j], bi[r - j]);
        lmin2(m, mj, m, mj, t, ti);
      }
      md[r] = m; mi[r] = mj;
    }
    #pragma unroll
    for (int j = 0; j < K_; j++) { d[j] = md[j]; ix[j] = mi[j]; }
  }
  if (lane == 0) {
    #pragma unroll
    for (int j = 0; j < K_; j++) idx10[wid * K_ + j] = ix[j];
  }
}

// ---------------------------------------------------------------------------
// Y32 + qp-GEMM fused by blockIdx.y (all branches fp32 scalar-A GEMM, TM=8):
//   y = 0,1 : Y1f/Y2f = q @ M1f[g], q @ M2f[g]
//   y = 2   : qp = q @ Wq
__global__ __launch_bounds__(384) void k_Y32(const float* __restrict__ q,
                                             const float* __restrict__ M1f,
                                             const float* __restrict__ M2f,
                                             const float* __restrict__ Wq,
                                             float* __restrict__ Y1f,
                                             float* __restrict__ Y2f,
                                             float* __restrict__ qp) {
  int c = threadIdx.x;
  int g = blockIdx.y;
  int r0 = blockIdx.x * 8;
  if (g < 2) {
    float a1[8], a2[8];
    #pragma unroll
    for (int r = 0; r < 8; r++) { a1[r] = 0.f; a2[r] = 0.f; }
    const float* m1 = M1f + (size_t)(g * C_) * C_ + c;
    const float* m2 = M2f + (size_t)(g * C_) * C_ + c;
    for (int k = 0; k < C_; k++) {
      float v1 = m1[(size_t)k * C_];
      float v2 = m2[(size_t)k * C_];
      #pragma unroll
      for (int r = 0; r < 8; r++) {
        float av = q[(r0 + r) * C_ + k];
        a1[r] = fmaf(av, v1, a1[r]);
        a2[r] = fmaf(av, v2, a2[r]);
      }
    }
    #pragma unroll
    for (int r = 0; r < 8; r++) {
      Y1f[((size_t)(r0 + r) * G_ + g) * C_ + c] = a1[r];
      Y2f[((size_t)(r0 + r) * G_ + g) * C_ + c] = a2[r];
    }
  } else {
    float acc[8];
    #pragma unroll
    for (int r = 0; r < 8; r++) acc[r] = 0.f;
    #pragma unroll 4
    for (int j = 0; j < C_; j++) {
      float w = Wq[j * C_ + c];
      #pragma unroll
      for (int r = 0; r < 8; r++) acc[r] = fmaf(q[(r0 + r) * C_ + j], w, acc[r]);
    }
    #pragma unroll
    for (int r = 0; r < 8; r++) qp[(r0 + r) * C_ + c] = acc[r];
  }
}

// ---------------------------------------------------------------------------
// FUSED fp32 MLP + top-3+r4 scan. 256 thr / 4 waves (81% occupancy config).
__global__ __launch_bounds__(256) void k_mlptop4(const float* __restrict__ Y1f,
                                                 const float* __restrict__ Y2f,
                                                 const int* __restrict__ idx10,
                                                 const float* __restrict__ q_pos,
                                                 const float* __restrict__ b1,
                                                 const float* __restrict__ ln_g,
                                                 const float* __restrict__ ln_b,
                                                 const float* __restrict__ W2,
                                                 const float4* __restrict__ pos4,
                                                 const float* __restrict__ q,
                                                 float* __restrict__ interp,
                                                 int* __restrict__ flags,
                                                 int* __restrict__ cnt) {
  int w_ = threadIdx.x >> 6, l = threadIdx.x & 63;
  int row = blockIdx.x * 4 + w_;
  int k = row % K_; int t = row / K_;
  int n = t % N_; t /= N_;
  int g = t % G_; int b = t / G_;
  int j = idx10[(b * N_ + n) * K_ + k];
  const float* y1 = Y1f + ((size_t)(b * N_ + j) * G_ + g) * C_;
  const float* y2 = Y2f + ((size_t)(b * N_ + n) * G_ + g) * C_;
  float x[6];
  #pragma unroll
  for (int jj = 0; jj < 6; jj++) {
    int col = l + 64 * jj;
    x[jj] = y1[col] + y2[col] + b1[col];
  }
  float sum = ((((x[0] + x[1]) + x[2]) + x[3]) + x[4]) + x[5];
  #pragma unroll
  for (int off = 1; off < 64; off <<= 1) sum += __shfl_xor(sum, off);
  float mu = sum * (1.0f / 384.0f);
  float sq = 0.f;
  #pragma unroll
  for (int jj = 0; jj < 6; jj++) { float dd = x[jj] - mu; sq = fmaf(dd, dd, sq); }
  #pragma unroll
  for (int off = 1; off < 64; off <<= 1) sq += __shfl_xor(sq, off);
  float var = sq * (1.0f / 384.0f);
  float rstd = 1.0f / sqrtf(var + 1e-5f);
  float ge[6];
  #pragma unroll
  for (int jj = 0; jj < 6; jj++) {
    int col = l + 64 * jj;
    float nv = (x[jj] - mu) * rstd * ln_g[col] + ln_b[col];
    ge[jj] = 0.5f * nv * (1.0f + erff(nv * 0.70710678118654752f));
  }
  float o3[3];
  #pragma unroll
  for (int o = 0; o < 3; o++) {
    float p = 0.f;
    #pragma unroll
    for (int jj = 0; jj < 6; jj++) {
      int col = l + 64 * jj;
      p = fmaf(ge[jj], W2[col * 3 + o], p);
    }
    #pragma unroll
    for (int off = 1; off < 64; off <<= 1) p += __shfl_xor(p, off);
    o3[o] = ftanh(p);
  }
  int gi = b * N_ + j;
  float px = q_pos[gi * 3 + 0] + o3[0];
  float py = q_pos[gi * 3 + 1] + o3[1];
  float pz = q_pos[gi * 3 + 2] + o3[2];
  float sp = fmaf(px, px, fmaf(py, py, pz * pz));
  float nx = -2.0f * px, ny = -2.0f * py, nz = -2.0f * pz;
  const float4* p4 = pos4 + b * N_;
  float d0 = INFINITY, d1 = INFINITY, d2 = INFINITY, r4 = INFINITY;
  int i0 = 0x7fffffff, i1 = 0x7fffffff, i2 = 0x7fffffff;
  for (int n0 = 0; n0 < N_; n0 += 64) {
    int nn = n0 + l;
    float4 pv = p4[nn];
    float v = fmaf(nx, pv.x, fmaf(ny, pv.y, fmaf(nz, pv.z, sp + pv.w)));
    bool c0 = v < d0, c1 = v < d1, c2 = v < d2;
    float disp = c2 ? d2 : v;
    r4 = fminf(r4, disp);
    d2 = c2 ? (c1 ? d1 : v) : d2;
    i2 = c2 ? (c1 ? i1 : nn) : i2;
    d1 = c1 ? (c0 ? d0 : v) : d1;
    i1 = c1 ? (c0 ? i0 : nn) : i1;
    d0 = c0 ? v : d0;
    i0 = c0 ? nn : i0;
  }
  #pragma unroll
  for (int off = 1; off < 64; off <<= 1) {
    float e0 = __shfl_xor(d0, off), e1 = __shfl_xor(d1, off), e2 = __shfl_xor(d2, off);
    float er = __shfl_xor(r4, off);
    int j0 = __shfl_xor(i0, off), j1 = __shfl_xor(i1, off), j2 = __shfl_xor(i2, off);
    float va = fmaxf(d0, e2), vb = fmaxf(d1, e1), vc = fmaxf(d2, e0);
    float r4n = fminf(fminf(r4, er), fminf(fminf(va, vb), vc));
    float m0d, t1d, u1d, m1d, t2a, t2b, u2d, w2d, m2d;
    int m0i, t1i, u1i, m1i, t2ai, t2bi, u2i, w2i, m2i;
    pmin2(m0d, m0i, d0, i0, e0, j0);
    pmax2(t1d, t1i, d0, i0, e0, j0);
    pmin2(u1d, u1i, d1, i1, e1, j1);
    pmin2(m1d, m1i, u1d, u1i, t1d, t1i);
    pmax2(t2a, t2ai, d1, i1, e0, j0);
    pmax2(t2b, t2bi, d0, i0, e1, j1);
    pmin2(u2d, u2i, d2, i2, e2, j2);
    pmin2(w2d, w2i, t2a, t2ai, t2b, t2bi);
    pmin2(m2d, m2i, u2d, u2i, w2d, w2i);
    d0 = m0d; i0 = m0i; d1 = m1d; i1 = m1i; d2 = m2d; i2 = m2i; r4 = r4n;
  }
  if (r4 - d2 < MARGIN_) {
    if (l == 0) {
      int pos = atomicAdd(cnt, 1);
      flags[pos] = row;
    }
    return;
  }
  float r0 = 1.0f / (d0 + 1e-8f);
  float r1 = 1.0f / (d1 + 1e-8f);
  float r2 = 1.0f / (d2 + 1e-8f);
  float rs = (r0 + r1) + r2;
  float w0 = r0 / rs, w1 = r1 / rs, w2 = r2 / rs;
  const float* qb = q + (size_t)b * N_ * C_ + g * GD_;
  const float* p0 = qb + (size_t)i0 * C_;
  const float* p1 = qb + (size_t)i1 * C_;
  const float* p2 = qb + (size_t)i2 * C_;
  float* op = interp + (((size_t)(b * N_ + n) * K_ + k) * C_) + g * GD_;
  #pragma unroll
  for (int cc0 = 0; cc0 < GD_; cc0 += 64) {
    int cc = cc0 + l;
    op[cc] = (w0 * p0[cc] + w1 * p1[cc]) + w2 * p2[cc];
  }
}

// ---------------------------------------------------------------------------
// Standalone fp64 fix (v-route), 256 thr, full VGPR budget
__global__ __launch_bounds__(256) void k_fix(const int* __restrict__ cnt,
                                             const int* __restrict__ flags,
                                             const float* __restrict__ q,
                                             const float* __restrict__ Wvoff,
                                             const float* __restrict__ Wq,
                                             const float* __restrict__ W1,
                                             const int* __restrict__ idx10,
                                             const float* __restrict__ q_pos,
                                             const double* __restrict__ s64,
                                             const float* __restrict__ b1,
                                             const float* __restrict__ ln_g,
                                             const float* __restrict__ ln_b,
                                             const float* __restrict__ W2,
                                             float* __restrict__ interp) {
  __shared__ double vbuf[4][2][GD_];   // 12.3 KB, per-wave scratch
  int w_ = threadIdx.x >> 6;
  int gwid = blockIdx.x * 4 + w_;
  int lane = threadIdx.x & 63;
  int nwaves = gridDim.x * 4;
  int total = cnt[0];
  for (int i = gwid; i < total; i += nwaves) {
    int wid = __builtin_amdgcn_readfirstlane(flags[i]);
    int m = wid % NK_; int t = wid / NK_;
    int g = t % G_; int b = t / G_;
    int n_ = m / K_, k_ = m % K_;
    int j = __builtin_amdgcn_readfirstlane(idx10[(b * N_ + n_) * K_ + k_]);
    const float* qj = q + (size_t)(b * N_ + j) * C_;   // wave-uniform
    const float* qn = q + (size_t)(b * N_ + n_) * C_;
    const float* wvo = Wvoff + g * GD_;
    const float* wqg = Wq + g * GD_;
    double a0 = 0.0, a1 = 0.0, a2 = 0.0, b0 = 0.0, b1a = 0.0, b2 = 0.0;
    for (int tt = 0; tt < C_; tt++) {
      double qjt = (double)qj[tt];
      double qnt = (double)qn[tt];
      const float* r1 = wvo + (size_t)tt * C_;
      const float* r2 = wqg + (size_t)tt * C_;
      a0 += qjt * (double)r1[lane];
      a1 += qjt * (double)r1[lane + 64];
      a2 += qjt * (double)r1[lane + 128];
      b0 += qnt * (double)r2[lane];
      b1a += qnt * (double)r2[lane + 64];
      b2 += qnt * (double)r2[lane + 128];
    }
    vbuf[w_][0][lane] = a0; vbuf[w_][0][lane + 64] = a1; vbuf[w_][0][lane + 128] = a2;
    vbuf[w_][1][lane] = b0; vbuf[w_][1][lane + 64] = b1a; vbuf[w_][1][lane + 128] = b2;
    double x[6];
    #pragma unroll
    for (int jj = 0; jj < 6; jj++) x[jj] = 0.0;
    for (int d = 0; d < GD_; d++) {
      double v1d = vbuf[w_][0][d];
      double v2d = vbuf[w_][1][d];
      const float* w1t = W1 + (size_t)d * C_;
      const float* w1b = W1 + (size_t)(GD_ + d) * C_;
      #pragma unroll
      for (int jj = 0; jj < 6; jj++) {
        int col = lane + 64 * jj;
        x[jj] += v1d * (double)w1t[col] + v2d * (double)w1b[col];
      }
    }
    #pragma unroll
    for (int jj = 0; jj < 6; jj++) x[jj] += (double)b1[lane + 64 * jj];
    double sum = ((((x[0] + x[1]) + x[2]) + x[3]) + x[4]) + x[5];
    #pragma unroll
    for (int off = 1; off < 64; off <<= 1) sum += __shfl_xor(sum, off);
    double mu = sum / 384.0;
    double sq = 0.0;
    #pragma unroll
    for (int jj = 0; jj < 6; jj++) { double dd = x[jj] - mu; sq += dd * dd; }
    #pragma unroll
    for (int off = 1; off < 64; off <<= 1) sq += __shfl_xor(sq, off);
    double var = sq / 384.0;
    double rstd = 1.0 / sqrt(var + 1e-5);
    double ge[6];
    #pragma unroll
    for (int jj = 0; jj < 6; jj++) {
      int col = lane + 64 * jj;
      double nv = (x[jj] - mu) * rstd * (double)ln_g[col] + (double)ln_b[col];
      ge[jj] = 0.5 * nv * (1.0 + erf(nv * 0.70710678118654752440));
    }
    double o3[3];
    #pragma unroll
    for (int o = 0; o < 3; o++) {
      double p = 0.0;
      #pragma unroll
      for (int jj = 0; jj < 6; jj++) {
        int col = lane + 64 * jj;
        p += ge[jj] * (double)W2[col * 3 + o];
      }
      #pragma unroll
      for (int off = 1; off < 64; off <<= 1) p += __shfl_xor(p, off);
      o3[o] = tanh(p);
    }
    int gi = b * N_ + j;
    double px = (double)q_pos[gi * 3 + 0] + o3[0];
    double py = (double)q_pos[gi * 3 + 1] + o3[1];
    double pz = (double)q_pos[gi * 3 + 2] + o3[2];
    double sp = px * px + py * py + pz * pz;
    const float* bp = q_pos + b * N_ * 3;
    const double* bs = s64 + b * N_;
    double d0 = INFINITY, d1 = INFINITY, d2 = INFINITY;
    int i0 = 0x7fffffff, i1 = 0x7fffffff, i2 = 0x7fffffff;
    for (int n = lane; n < N_; n += 64) {
      double dot = px * (double)bp[3 * n] + py * (double)bp[3 * n + 1] +
                   pz * (double)bp[3 * n + 2];
      double dd = (sp - 2.0 * dot) + bs[n];
      bool c0 = lless(dd, n, d0, i0);
      bool c1 = lless(dd, n, d1, i1);
      bool c2 = lless(dd, n, d2, i2);
      double nd2 = c2 ? (c1 ? d1 : dd) : d2; int ni2 = c2 ? (c1 ? i1 : n) : i2;
      double nd1 = c1 ? (c0 ? d0 : dd) : d1; int ni1 = c1 ? (c0 ? i0 : n) : i1;
      double nd0 = c0 ? dd : d0;             int ni0 = c0 ? n : i0;
      d0 = nd0; d1 = nd1; d2 = nd2; i0 = ni0; i1 = ni1; i2 = ni2;
    }
    #pragma unroll
    for (int off = 1; off < 64; off <<= 1) {
      double e0 = __shfl_xor(d0, off), e1 = __shfl_xor(d1, off), e2 = __shfl_xor(d2, off);
      int j0 = __shfl_xor(i0, off), j1 = __shfl_xor(i1, off), j2 = __shfl_xor(i2, off);
      double mnd, mxd, p1d, q1d, q2d, q3d, q4d, t1d, t2d;
      int mni, mxi, p1i, q1i, q2i, q3i, q4i, t1i, t2i;
      lmin2(mnd, mni, d0, i0, e0, j0);
      lmax2(mxd, mxi, d0, i0, e0, j0);
      lmin2(p1d, p1i, d1, i1, e1, j1);
      lmin2(t1d, t1i, p1d, p1i, mxd, mxi);
      lmax2(q1d, q1i, d1, i1, e0, j0);
      lmax2(q2d, q2i, d0, i0, e1, j1);
      lmin2(q3d, q3i, q1d, q1i, q2d, q2i);
      lmin2(q4d, q4i, d2, i2, e2, j2);
      lmin2(t2d, t2i, q3d, q3i, q4d, q4i);
      d0 = mnd; i0 = mni; d1 = t1d; i1 = t1i; d2 = t2d; i2 = t2i;
    }
    double r0 = 1.0 / (d0 + 1e-8);
    double r1 = 1.0 / (d1 + 1e-8);
    double r2 = 1.0 / (d2 + 1e-8);
    double rs = (r0 + r1) + r2;
    float w0 = (float)(r0 / rs), w1 = (float)(r1 / rs), w2 = (float)(r2 / rs);
    const float* qb = q + (size_t)b * N_ * C_ + g * GD_;
    const float* p0 = qb + (size_t)i0 * C_;
    const float* p1 = qb + (size_t)i1 * C_;
    const float* p2 = qb + (size_t)i2 * C_;
    float* op = interp + (((size_t)(b * N_ + n_) * K_ + k_) * C_) + g * GD_;
    #pragma unroll
    for (int cc0 = 0; cc0 < GD_; cc0 += 64) {
      int cc = cc0 + lane;
      op[cc] = (w0 * p0[cc] + w1 * p1[cc]) + w2 * p2[cc];
    }
  }
}

// ---------------------------------------------------------------------------
// Standalone k_U: U[bn][h][c] = sum_d qp[bn, h*64+d] * Wk[c, h*64+d]
__global__ __launch_bounds__(384) void k_U(const float* __restrict__ qp,
                                           const float* __restrict__ WkT,
                                           float* __restrict__ U) {
  int c = threadIdx.x;
  int r0 = blockIdx.x * 8;
  for (int h = 0; h < 6; h++) {
    float acc[8];
    #pragma unroll
    for (int r = 0; r < 8; r++) acc[r] = 0.f;
    #pragma unroll 4
    for (int dd = 0; dd < 64; dd++) {
      float w = WkT[(h * 64 + dd) * C_ + c];
      #pragma unroll
      for (int r = 0; r < 8; r++)
        acc[r] = fmaf(qp[(r0 + r) * C_ + h * 64 + dd], w, acc[r]);
    }
    #pragma unroll
    for (int r = 0; r < 8; r++) U[((size_t)(r0 + r) * 6 + h) * C_ + c] = acc[r];
  }
}

// ---------------------------------------------------------------------------
// attention per bn (ONE wave, 6 heads serial; interp row cached in VGPRs)
__global__ __launch_bounds__(384) void k_attn2(const float* __restrict__ interp,
                                               float* __restrict__ Umix) {
  int bn = blockIdx.x * 6 + (threadIdx.x >> 6);
  int lane = threadIdx.x & 63;
  if (bn >= B_ * N_) return;
  float ipv[K_][6];
  const float* ip0 = interp + (size_t)bn * K_ * C_;
  #pragma unroll
  for (int k = 0; k < K_; k++) {
    #pragma unroll
    for (int j = 0; j < 6; j++) ipv[k][j] = ip0[k * C_ + lane + 64 * j];
  }
  float* ubase = Umix + (size_t)bn * 6 * C_;
  for (int h = 0; h < 6; h++) {
    float u[6];
    #pragma unroll
    for (int j = 0; j < 6; j++) u[j] = ubase[h * C_ + lane + 64 * j];
    float logit[K_];
    #pragma unroll
    for (int k = 0; k < K_; k++) {
      float p = 0.f;
      #pragma unroll
      for (int j = 0; j < 6; j++) p = fmaf(ipv[k][j], u[j], p);
      #pragma unroll
      for (int off = 1; off < 64; off <<= 1) p += __shfl_xor(p, off);
      logit[k] = p * SCALE_;
    }
    float mx = logit[0];
    #pragma unroll
    for (int k = 1; k < K_; k++) mx = fmaxf(mx, logit[k]);
    float e[K_], se = 0.f;
    #pragma unroll
    for (int k = 0; k < K_; k++) { e[k] = __expf(logit[k] - mx); se += e[k]; }
    float inv = 1.0f / se;
    #pragma unroll
    for (int k = 0; k < K_; k++) e[k] *= inv;
    #pragma unroll
    for (int j = 0; j < 6; j++) {
      float mv = 0.f;
      #pragma unroll
      for (int k = 0; k < K_; k++) mv = fmaf(e[k], ipv[k][j], mv);
      ubase[h * C_ + lane + 64 * j] = mv;
    }
  }
}

// ---------------------------------------------------------------------------
// outproj: attn_out = mix @ Wv (per-head) -> LDS -> out = attn_out @ Wproj + b
__global__ __launch_bounds__(384) void k_outproj(const float* __restrict__ mix,
                                                 const float* __restrict__ Wv,
                                                 const float* __restrict__ Wproj,
                                                 const float* __restrict__ bproj,
                                                 float* __restrict__ out) {
  __shared__ float ao[8][C_];
  int c = threadIdx.x;
  int h = __builtin_amdgcn_readfirstlane(threadIdx.x) >> 6;  // wave-uniform
  int r0 = blockIdx.x * 8;
  float acc[8];
  #pragma unroll
  for (int r = 0; r < 8; r++) acc[r] = 0.f;
  #pragma unroll 4
  for (int ci = 0; ci < C_; ci++) {
    float w = Wv[ci * C_ + c];
    #pragma unroll
    for (int r = 0; r < 8; r++)
      acc[r] = fmaf(mix[((size_t)(r0 + r) * 6 + h) * C_ + ci], w, acc[r]);
  }
  #pragma unroll
  for (int r = 0; r < 8; r++) ao[r][c] = acc[r];
  __syncthreads();
  float a2[8];
  #pragma unroll
  for (int r = 0; r < 8; r++) a2[r] = 0.f;
  #pragma unroll 4
  for (int ci = 0; ci < C_; ci++) {
    float w = Wproj[ci * C_ + c];
    #pragma unroll
    for (int r = 0; r < 8; r++) a2[r] = fmaf(ao[r][ci], w, a2[r]);
  }
  float bv = bproj[c];
  #pragma unroll
  for (int r = 0; r < 8; r++) out[(size_t)(r0 + r) * C_ + c] = a2[r] + bv;
}

// ---------------------------------------------------------------------------
extern "C" void kernel_launch(void* const* d_in, const int* in_sizes, int n_in,
                              void* d_out, int out_size, void* d_ws, size_t ws_size,
                              hipStream_t stream) {
  const float* q     = (const float*)d_in[0];
  const float* q_pos = (const float*)d_in[1];
  const float* Wq    = (const float*)d_in[2];
  const float* Wk    = (const float*)d_in[3];
  const float* Wv    = (const float*)d_in[4];
  const float* Wvoff = (const float*)d_in[5];
  const float* W1    = (const float*)d_in[6];
  const float* b1    = (const float*)d_in[7];
  const float* ln_g  = (const float*)d_in[8];
  const float* ln_b  = (const float*)d_in[9];
  const float* W2    = (const float*)d_in[10];
  const float* Wproj = (const float*)d_in[11];
  const float* bproj = (const float*)d_in[12];
  float* out = (float*)d_out;

  char* ws = (char*)d_ws;
  // U0 (38 MB): Y1f/Y2f/M1f/M2f during prep+scan; reused as Umix from k_U on.
  char* U0 = ws; ws += 38 * 1024 * 1024;
  float*  Y1f    = (float*)(U0);                         // 12.58 MB
  float*  Y2f    = (float*)(U0 + 12582912);              // 12.58 MB
  float*  M1f    = (float*)(U0 + 25165824);              // 1.18 MB
  float*  M2f    = (float*)(U0 + 26345472);              // 1.18 MB
  float*  Umix   = (float*)U0;                           // 37.75 MB (from k_U)
  // Persistent (outside U0; live across the U0 reuse boundary)
  double* s64    = (double*)ws; ws += (size_t)B_ * N_ * 8;              // 32 KB
  float*  qp32   = (float*)ws;  ws += (size_t)B_ * N_ * C_ * 4;         // 6.29 MB
  float*  interp = (float*)ws;  ws += (size_t)B_ * N_ * K_ * C_ * 4;    // 62.9 MB
  float*  WkT    = (float*)ws;  ws += (size_t)C_ * C_ * 4;              // 0.59 MB
  int*    idx10  = (int*)ws;    ws += (size_t)B_ * N_ * K_ * 4;         // 160 KB
  int*    flags  = (int*)ws;    ws += (size_t)M2_ * 4;                  // 320 KB
  float4* pos4   = (float4*)ws; ws += (size_t)B_ * N_ * 16;             // 64 KB
  int*    cnt    = (int*)ws;    ws += 256;                              // 4 B

  k_L1<<<L1_GRID_, 384, 0, stream>>>(Wvoff, Wq, W1, Wk, q_pos, M1f, M2f, WkT,
                                     s64, pos4, cnt);
  k_knn10_w<<<B_ * N_ / 4, 256, 0, stream>>>(q_pos, s64, idx10);
  k_Y32<<<dim3(B_ * N_ / 8, 3), 384, 0, stream>>>(q, M1f, M2f, Wq, Y1f, Y2f, qp32);
  k_mlptop4<<<M2_ / 4, 256, 0, stream>>>(Y1f, Y2f, idx10, q_pos, b1, ln_g, ln_b,
                                         W2, pos4, q, interp, flags, cnt);
  k_fix<<<512, 256, 0, stream>>>(cnt, flags, q, Wvoff, Wq, W1, idx10, q_pos, s64,
                                 b1, ln_g, ln_b, W2, interp);
  k_U<<<B_ * N_ / 8, 384, 0, stream>>>(qp32, WkT, Umix);
  k_attn2<<<(B_ * N_ + 5) / 6, 384, 0, stream>>>(interp, Umix);
  k_outproj<<<B_ * N_ / 8, 384, 0, stream>>>(Umix, Wv, Wproj, bproj, out);
}